// Round 17
// baseline (426.645 us; speedup 1.0000x reference)
//
#include <hip/hip_runtime.h>
#include <hip/hip_cooperative_groups.h>
#include <math.h>

namespace cg = cooperative_groups;

#define N3 262144           // 64^3

// ===========================================================================
// Derived-feature formulation (verified R4-R15). R17: cooperative fusion with
// 1-D grid + checked launch + deterministic fallback to the verified R15
// split path. y lives in d_out between passes; fused conv2 is in-place on
// d_out (reads pre-sync, writes post-sync). ws base = zpre (fallback) OR
// gbuf (fused), exclusive per pass.
// ===========================================================================

// Table layout (floats):
// conv1 (448): T1c[8][24]@0, T1f[8][24]@192, T1v[8][8]@384
// conv2 (1280)@448: T2c[16][24]@+0, T2f[16][24]@+384, T2sv[16][8]@+768,
//   T2vs[8][24]@+896, T2v0c[8][8]@+1088, T2v0f[8][8]@+1152, T2v1[8][8]@+1216
#define TBL_TOTAL 1728

__device__ inline void lattice_emb(int p, float* embr) {
    int i = p / 9, j = (p / 3) % 3, k = p % 3;
    float gx = (float)(i - 1), gy = (float)(j - 1), gz = (float)(k - 1);
    float r = sqrtf(gx * gx + gy * gy + gz * gz);
    const float centers[4] = {0.f, 0.33333334f, 0.6666667f, 1.f};
    const float step = 0.33333334f;
    #pragma unroll
    for (int b = 0; b < 4; b++) {
        float dd = (r - centers[b]) / step;
        float e = 0.f;
        if (fabsf(dd) < 1.f)
            e = 1.14136f * expf(2.f) * expf(-1.f / fmaxf(1.f - dd * dd, 1e-9f));
        embr[b] = e;
    }
}

// Also zeroes the BN stats buffers (threads TBL_TOTAL..TBL_TOTAL+143).
__global__ __launch_bounds__(256) void build_tables_kernel(
        const float* __restrict__ w1,  const float* __restrict__ sc1,
        const float* __restrict__ w2,  const float* __restrict__ sc2s,
        const float* __restrict__ sc2v, float* __restrict__ T,
        float* __restrict__ stats1, float* __restrict__ stats2) {
    int gid = blockIdx.x * 256 + threadIdx.x;
    if (gid >= TBL_TOTAL) {
        int r = gid - TBL_TOTAL;
        if (r < 72) stats1[r] = 0.f;
        else if (r < 144) stats2[r - 72] = 0.f;
        return;
    }

    const float inv_ks15 = 0.19245008972987526f;  // 1/3^1.5
    const float s3   = 1.7320508075688772f;
    const float a1   = 0.35355339059327373f;  // 1/sqrt(8)
    const float a_s  = 0.2041241452319315f;   // 1/sqrt(24)
    const float a_v  = 0.17677669529663687f;  // 1/sqrt(32)
    const float a_s3 = 0.11785113019775793f;  // a_s/sqrt(3)
    const float a_v6 = 0.07216878364870322f;  // a_v/sqrt(6)

    float embC[4], embF[4];
    lattice_emb(13, embC);   // center (r=0)
    lattice_emb(22, embF);   // face   (r=1), shared by all 6 faces

    auto WC1 = [&](int c) { float s=0.f;
        #pragma unroll
        for (int b=0;b<4;b++) s += embC[b]*w1[b*256+c]; return s*inv_ks15; };
    auto WF1 = [&](int c) { float s=0.f;
        #pragma unroll
        for (int b=0;b<4;b++) s += embF[b]*w1[b*256+c]; return s*inv_ks15; };
    auto WC2 = [&](int c) { float s=0.f;
        #pragma unroll
        for (int b=0;b<4;b++) s += embC[b]*w2[b*832+c]; return s*inv_ks15; };
    auto WF2 = [&](int c) { float s=0.f;
        #pragma unroll
        for (int b=0;b<4;b++) s += embF[b]*w2[b*832+c]; return s*inv_ks15; };

    float val = 0.f;
    if (gid < 192) {                       // T1c
        int i = gid / 24, o = gid % 24;
        int c = (o < 16) ? i * 16 + o : 128 + i * 8 + (o - 16);
        val = a1 * WC1(c) + a1 * sc1[i * 24 + o];
    } else if (gid < 384) {                // T1f
        int r = gid - 192; int i = r / 24, o = r % 24;
        int c = (o < 16) ? i * 16 + o : 128 + i * 8 + (o - 16);
        val = a1 * WF1(c);
    } else if (gid < 448) {                // T1v
        int r = gid - 384; int i = r / 8, jj = r % 8;
        val = a1 * s3 * WF1(192 + i * 8 + jj);
    } else if (gid < 832) {                // T2c
        int r = gid - 448; int i = r / 24, o = r % 24;
        int c = (o < 16) ? i * 16 + o : 256 + i * 8 + (o - 16);
        val = a_s * WC2(c) + 0.25f * sc2s[i * 24 + o];
    } else if (gid < 1216) {               // T2f
        int r = gid - 832; int i = r / 24, o = r % 24;
        int c = (o < 16) ? i * 16 + o : 256 + i * 8 + (o - 16);
        val = a_s * WF2(c);
    } else if (gid < 1344) {               // T2sv
        int r = gid - 1216; int i = r / 8, jj = r % 8;
        val = a_v * s3 * WF2(384 + i * 8 + jj);
    } else if (gid < 1536) {               // T2vs
        int r = gid - 1344; int u = r / 24, o = r % 24;
        int c = (o < 16) ? 576 + u * 16 + o : 704 + u * 8 + (o - 16);
        val = a_s3 * s3 * WF2(c);
    } else if (gid < 1600) {               // T2v0c
        int r = gid - 1536; int u = r / 8, jj = r % 8;
        val = a_v * WC2(512 + u * 8 + jj) + a1 * sc2v[u * 8 + jj];
    } else if (gid < 1664) {               // T2v0f
        int r = gid - 1600; int u = r / 8, jj = r % 8;
        val = a_v * WF2(512 + u * 8 + jj);
    } else {                               // T2v1
        int r = gid - 1664; int u = r / 8, jj = r % 8;
        val = a_v6 * s3 * WF2(768 + u * 8 + jj);
    }
    T[gid] = val;
}

// ---------------------------------------------------------------------------
// float4 helpers
// ---------------------------------------------------------------------------
__device__ inline float4 f4z() { return make_float4(0.f, 0.f, 0.f, 0.f); }
__device__ inline float4 f4add(float4 a, float4 b) {
    return make_float4(a.x+b.x, a.y+b.y, a.z+b.z, a.w+b.w); }
__device__ inline float4 f4sub(float4 a, float4 b) {
    return make_float4(a.x-b.x, a.y-b.y, a.z-b.z, a.w-b.w); }
__device__ inline float4 f4fma(float s, float4 a, float4 c) {
    return make_float4(fmaf(s,a.x,c.x), fmaf(s,a.y,c.y), fmaf(s,a.z,c.z), fmaf(s,a.w,c.w)); }
__device__ inline float f4sum(float4 a) { return a.x+a.y+a.z+a.w; }
__device__ inline float f4dot(float4 a) { return a.x*a.x+a.y*a.y+a.z*a.z+a.w*a.w; }
__device__ inline float sigm(float v) { return 1.0f / (1.0f + expf(-v)); }

#define LQ5(BP, C_, DM_, DP_, HM_, HP_)                                       \
    {                                                                         \
        const float* _p = (BP);                                               \
        C_  = *(const float4*)_p;                                             \
        DM_ = dmok ? *(const float4*)(_p - 4096) : f4z();                     \
        DP_ = dpok ? *(const float4*)(_p + 4096) : f4z();                     \
        HM_ = hmok ? *(const float4*)(_p -   64) : f4z();                     \
        HP_ = hpok ? *(const float4*)(_p +   64) : f4z();                     \
    }

#define WQ(C_, WM_, WP_)                                                      \
    {                                                                         \
        float _lw = __shfl_up((C_).w, 1, 64);                                 \
        float _rw = __shfl_down((C_).x, 1, 64);                               \
        WM_ = make_float4(wL ? 0.f : _lw, (C_).x, (C_).y, (C_).z);            \
        WP_ = make_float4((C_).y, (C_).z, (C_).w, wR ? 0.f : _rw);            \
    }

// Conv bodies: compute acc[24] for the given half. Shared by plain & fused.
#define CONV1_BODY(SRC)                                                       \
    {                                                                         \
        float4 nc, ndm, ndp, nhm, nhp;                                        \
        LQ5((SRC) + idx, nc, ndm, ndp, nhm, nhp);                             \
        if (ohalf == 0) {                                                     \
            _Pragma("unroll 1")                                               \
            for (int i = 0; i < 8; i++) {                                     \
                float4 c = nc, dmq = ndm, dpq = ndp, hmq = nhm, hpq = nhp;    \
                if (i < 7) LQ5((SRC) + (i + 1) * N3 + idx, nc, ndm, ndp, nhm, nhp); \
                float4 wmq, wpq; WQ(c, wmq, wpq);                             \
                float4 S = f4add(f4add(f4add(dmq, dpq), f4add(hmq, hpq)), f4add(wmq, wpq)); \
                const float* tc = &T[i * 24];                                 \
                const float* tf = &T[192 + i * 24];                           \
                _Pragma("unroll")                                             \
                for (int o = 0; o < 24; o++)                                  \
                    acc[o] = f4fma(tc[o], c, f4fma(tf[o], S, acc[o]));        \
            }                                                                 \
        } else {                                                              \
            _Pragma("unroll 1")                                               \
            for (int i = 0; i < 8; i++) {                                     \
                float4 c = nc, dmq = ndm, dpq = ndp, hmq = nhm, hpq = nhp;    \
                if (i < 7) LQ5((SRC) + (i + 1) * N3 + idx, nc, ndm, ndp, nhm, nhp); \
                float4 wmq, wpq; WQ(c, wmq, wpq);                             \
                float4 Dd = f4sub(dpq, dmq), Dh = f4sub(hpq, hmq), Dw = f4sub(wpq, wmq); \
                const float* tv = &T[384 + i * 8];                            \
                _Pragma("unroll")                                             \
                for (int jj = 0; jj < 8; jj++) {                              \
                    float wv = tv[jj];                                        \
                    acc[jj * 3 + 0] = f4fma(wv, Dd, acc[jj * 3 + 0]);         \
                    acc[jj * 3 + 1] = f4fma(wv, Dh, acc[jj * 3 + 1]);         \
                    acc[jj * 3 + 2] = f4fma(wv, Dw, acc[jj * 3 + 2]);         \
                }                                                             \
            }                                                                 \
        }                                                                     \
    }

#define CONV2_BODY(SRC)                                                       \
    if (ohalf == 0) {                                                         \
        float4 nc, ndm, ndp, nhm, nhp;                                        \
        LQ5((SRC) + idx, nc, ndm, ndp, nhm, nhp);                             \
        _Pragma("unroll 1")                                                   \
        for (int i = 0; i < 16; i++) {                                        \
            float4 c = nc, dmq = ndm, dpq = ndp, hmq = nhm, hpq = nhp;        \
            if (i < 15) LQ5((SRC) + (i + 1) * N3 + idx, nc, ndm, ndp, nhm, nhp); \
            float4 wmq, wpq; WQ(c, wmq, wpq);                                 \
            float4 S = f4add(f4add(f4add(dmq, dpq), f4add(hmq, hpq)), f4add(wmq, wpq)); \
            const float* tc = &T[i * 24];                                     \
            const float* tf = &T[384 + i * 24];                               \
            _Pragma("unroll")                                                 \
            for (int o = 0; o < 24; o++)                                      \
                acc[o] = f4fma(tc[o], c, f4fma(tf[o], S, acc[o]));            \
        }                                                                     \
        _Pragma("unroll 1")                                                   \
        for (int u = 0; u < 8; u++) {                                         \
            const float* b0 = (SRC) + (16 + u * 3) * N3 + idx;                \
            float4 qdm = dmok ? *(const float4*)(b0 - 4096) : f4z();          \
            float4 qdp = dpok ? *(const float4*)(b0 + 4096) : f4z();          \
            float4 qhm = hmok ? *(const float4*)(b0 + N3 - 64) : f4z();       \
            float4 qhp = hpok ? *(const float4*)(b0 + N3 + 64) : f4z();       \
            float4 c2  = *(const float4*)(b0 + 2 * N3);                       \
            float4 wmq, wpq; WQ(c2, wmq, wpq);                                \
            float4 Dsum = f4add(f4add(f4sub(qdp, qdm), f4sub(qhp, qhm)), f4sub(wpq, wmq)); \
            const float* tvs = &T[896 + u * 24];                              \
            _Pragma("unroll")                                                 \
            for (int o = 0; o < 24; o++)                                      \
                acc[o] = f4fma(tvs[o], Dsum, acc[o]);                         \
        }                                                                     \
    } else {                                                                  \
        float4 nc, ndm, ndp, nhm, nhp;                                        \
        LQ5((SRC) + idx, nc, ndm, ndp, nhm, nhp);                             \
        _Pragma("unroll 1")                                                   \
        for (int i = 0; i < 16; i++) {                                        \
            float4 c = nc, dmq = ndm, dpq = ndp, hmq = nhm, hpq = nhp;        \
            if (i < 15) LQ5((SRC) + (i + 1) * N3 + idx, nc, ndm, ndp, nhm, nhp); \
            float4 wmq, wpq; WQ(c, wmq, wpq);                                 \
            float4 Dd = f4sub(dpq, dmq), Dh = f4sub(hpq, hmq), Dw = f4sub(wpq, wmq); \
            const float* tv = &T[768 + i * 8];                                \
            _Pragma("unroll")                                                 \
            for (int jj = 0; jj < 8; jj++) {                                  \
                float wv = tv[jj];                                            \
                acc[jj * 3 + 0] = f4fma(wv, Dd, acc[jj * 3 + 0]);             \
                acc[jj * 3 + 1] = f4fma(wv, Dh, acc[jj * 3 + 1]);             \
                acc[jj * 3 + 2] = f4fma(wv, Dw, acc[jj * 3 + 2]);             \
            }                                                                 \
        }                                                                     \
        _Pragma("unroll 1")                                                   \
        for (int u = 0; u < 8; u++) {                                         \
            const float* t0c = &T[1088 + u * 8];                              \
            const float* t0f = &T[1152 + u * 8];                              \
            const float* tv1 = &T[1216 + u * 8];                              \
            {                                                                 \
                float4 c, dmq, dpq, hmq, hpq;                                 \
                LQ5((SRC) + (16 + u * 3 + 0) * N3 + idx, c, dmq, dpq, hmq, hpq); \
                float4 wmq, wpq; WQ(c, wmq, wpq);                             \
                float4 S = f4add(f4add(f4add(dmq, dpq), f4add(hmq, hpq)), f4add(wmq, wpq)); \
                float4 Dh = f4sub(hpq, hmq), Dw = f4sub(wpq, wmq);            \
                _Pragma("unroll")                                             \
                for (int jj = 0; jj < 8; jj++) {                              \
                    float k1 = tv1[jj];                                       \
                    acc[jj * 3 + 0] = f4fma(t0c[jj], c, f4fma(t0f[jj], S, acc[jj * 3 + 0])); \
                    acc[jj * 3 + 2] = f4fma(k1, Dh, acc[jj * 3 + 2]);         \
                    acc[jj * 3 + 1] = f4fma(-k1, Dw, acc[jj * 3 + 1]);        \
                }                                                             \
            }                                                                 \
            {                                                                 \
                float4 c, dmq, dpq, hmq, hpq;                                 \
                LQ5((SRC) + (16 + u * 3 + 1) * N3 + idx, c, dmq, dpq, hmq, hpq); \
                float4 wmq, wpq; WQ(c, wmq, wpq);                             \
                float4 S = f4add(f4add(f4add(dmq, dpq), f4add(hmq, hpq)), f4add(wmq, wpq)); \
                float4 Dd = f4sub(dpq, dmq), Dw = f4sub(wpq, wmq);            \
                _Pragma("unroll")                                             \
                for (int jj = 0; jj < 8; jj++) {                              \
                    float k1 = tv1[jj];                                       \
                    acc[jj * 3 + 1] = f4fma(t0c[jj], c, f4fma(t0f[jj], S, acc[jj * 3 + 1])); \
                    acc[jj * 3 + 0] = f4fma(k1, Dw, acc[jj * 3 + 0]);         \
                    acc[jj * 3 + 2] = f4fma(-k1, Dd, acc[jj * 3 + 2]);        \
                }                                                             \
            }                                                                 \
            {                                                                 \
                float4 c, dmq, dpq, hmq, hpq;                                 \
                LQ5((SRC) + (16 + u * 3 + 2) * N3 + idx, c, dmq, dpq, hmq, hpq); \
                float4 wmq, wpq; WQ(c, wmq, wpq);                             \
                float4 S = f4add(f4add(f4add(dmq, dpq), f4add(hmq, hpq)), f4add(wmq, wpq)); \
                float4 Dd = f4sub(dpq, dmq), Dh = f4sub(hpq, hmq);            \
                _Pragma("unroll")                                             \
                for (int jj = 0; jj < 8; jj++) {                              \
                    float k1 = tv1[jj];                                       \
                    acc[jj * 3 + 2] = f4fma(t0c[jj], c, f4fma(t0f[jj], S, acc[jj * 3 + 2])); \
                    acc[jj * 3 + 1] = f4fma(k1, Dd, acc[jj * 3 + 1]);         \
                    acc[jj * 3 + 0] = f4fma(-k1, Dh, acc[jj * 3 + 0]);        \
                }                                                             \
            }                                                                 \
        }                                                                     \
    }

// Stats reduction + atomics (4 waves/block)
#define STATS_REDUCE(STATS)                                                   \
    {                                                                         \
        int lane = threadIdx.x & 63, wvx = threadIdx.x >> 6;                  \
        if (ohalf == 0) {                                                     \
            _Pragma("unroll")                                                 \
            for (int q = 0; q < 48; q++) {                                    \
                float val = (q < 24) ? f4sum(acc[q]) : f4dot(acc[q - 24]);    \
                _Pragma("unroll")                                             \
                for (int mq = 32; mq >= 1; mq >>= 1) val += __shfl_xor(val, mq, 64); \
                if (lane == 0) red[wvx][q] = val;                             \
            }                                                                 \
            __syncthreads();                                                  \
            if (threadIdx.x < 48)                                             \
                atomicAdd(&(STATS)[threadIdx.x],                              \
                          red[0][threadIdx.x] + red[1][threadIdx.x] +         \
                          red[2][threadIdx.x] + red[3][threadIdx.x]);         \
        } else {                                                              \
            _Pragma("unroll")                                                 \
            for (int q = 0; q < 24; q++) {                                    \
                float val = f4dot(acc[q]);                                    \
                _Pragma("unroll")                                             \
                for (int mq = 32; mq >= 1; mq >>= 1) val += __shfl_xor(val, mq, 64); \
                if (lane == 0) red[wvx][q] = val;                             \
            }                                                                 \
            __syncthreads();                                                  \
            if (threadIdx.x < 24)                                             \
                atomicAdd(&(STATS)[48 + threadIdx.x],                         \
                          red[0][threadIdx.x] + red[1][threadIdx.x] +         \
                          red[2][threadIdx.x] + red[3][threadIdx.x]);         \
        }                                                                     \
    }

#define FINALIZE_SB(STATS, WSC, BSC, WVC)                                     \
    if (threadIdx.x < 32) {                                                   \
        int t = threadIdx.x;                                                  \
        const float invN = 1.0f / 262144.0f;                                  \
        if (t < 24) {                                                         \
            float mu = (STATS)[t] * invN;                                     \
            float var = (STATS)[24 + t] * invN - mu * mu;                     \
            float inv = rsqrtf(var + 1e-5f);                                  \
            sb[t] = (WSC)[t] * inv;                                           \
            sb[24 + t] = (BSC)[t] - mu * (WSC)[t] * inv;                      \
        } else {                                                              \
            int u = t - 24;                                                   \
            float s2 = (STATS)[48 + u * 3] + (STATS)[48 + u * 3 + 1] +        \
                       (STATS)[48 + u * 3 + 2];                               \
            sb[48 + u] = (WVC)[u] * rsqrtf(s2 * invN + 1e-5f);                \
        }                                                                     \
    }                                                                         \
    __syncthreads();

// Gated epilogue writing final 40-ch output from register acc
#define GATED_EPILOGUE(DST, GBUF)                                             \
    if (ohalf == 0) {                                                         \
        _Pragma("unroll")                                                     \
        for (int c = 0; c < 16; c++) {                                        \
            float4 v = acc[c];                                                \
            float scl = sb[c], bi = sb[24 + c];                               \
            float4 r;                                                         \
            r.x = fmaxf(v.x * scl + bi, 0.f);                                 \
            r.y = fmaxf(v.y * scl + bi, 0.f);                                 \
            r.z = fmaxf(v.z * scl + bi, 0.f);                                 \
            r.w = fmaxf(v.w * scl + bi, 0.f);                                 \
            *(float4*)((DST) + c * N3 + idx) = r;                             \
        }                                                                     \
    } else {                                                                  \
        _Pragma("unroll 1")                                                   \
        for (int u = 0; u < 8; u++) {                                         \
            float4 gv = *(const float4*)((GBUF) + u * N3 + idx);              \
            float scl = sb[16 + u], bi = sb[40 + u], sv = sb[48 + u];         \
            float4 g;                                                         \
            g.x = sigm(gv.x * scl + bi) * sv;                                 \
            g.y = sigm(gv.y * scl + bi) * sv;                                 \
            g.z = sigm(gv.z * scl + bi) * sv;                                 \
            g.w = sigm(gv.w * scl + bi) * sv;                                 \
            _Pragma("unroll")                                                 \
            for (int m = 0; m < 3; m++) {                                     \
                float4 a = acc[u * 3 + m];                                    \
                float4 r = make_float4(a.x * g.x, a.y * g.y, a.z * g.z, a.w * g.w); \
                *(float4*)((DST) + (16 + u * 3 + m) * N3 + idx) = r;          \
            }                                                                 \
        }                                                                     \
    }

// ---------------------------------------------------------------------------
// PLAIN kernels (R15-verified fallback path)
// ---------------------------------------------------------------------------
__global__ __launch_bounds__(256, 2) void conv1_plain(const float* __restrict__ x,
                                                      const float* __restrict__ Tg,
                                                      float* __restrict__ out,
                                                      float* __restrict__ stats) {
    __shared__ float T[448];
    __shared__ float red[4][48];
    for (int t = threadIdx.x; t < 448; t += 256) T[t] = Tg[t];
    __syncthreads();
    const int ohalf = blockIdx.y;
    int idx = blockIdx.x * 1024 + threadIdx.x * 4;
    int w0 = idx & 63, h = (idx >> 6) & 63, d = idx >> 12;
    bool dmok = d > 0, dpok = d < 63, hmok = h > 0, hpok = h < 63;
    bool wL = (w0 == 0), wR = (w0 == 60);
    float4 acc[24];
    #pragma unroll
    for (int o = 0; o < 24; o++) acc[o] = f4z();
    CONV1_BODY(x);
    int obase = ohalf * 24;
    #pragma unroll
    for (int o = 0; o < 24; o++)
        *(float4*)(out + (obase + o) * N3 + idx) = acc[o];
    STATS_REDUCE(stats);
}

__global__ __launch_bounds__(256, 2) void conv2_plain(const float* __restrict__ y,
                                                      const float* __restrict__ Tg,
                                                      float* __restrict__ out,
                                                      float* __restrict__ stats) {
    __shared__ float T[1280];
    __shared__ float red[4][48];
    for (int t = threadIdx.x; t < 1280; t += 256) T[t] = Tg[448 + t];
    __syncthreads();
    const int ohalf = blockIdx.y;
    int idx = blockIdx.x * 1024 + threadIdx.x * 4;
    int w0 = idx & 63, h = (idx >> 6) & 63, d = idx >> 12;
    bool dmok = d > 0, dpok = d < 63, hmok = h > 0, hpok = h < 63;
    bool wL = (w0 == 0), wR = (w0 == 60);
    float4 acc[24];
    #pragma unroll
    for (int o = 0; o < 24; o++) acc[o] = f4z();
    CONV2_BODY(y);
    int obase = ohalf * 24;
    #pragma unroll
    for (int o = 0; o < 24; o++)
        *(float4*)(out + (obase + o) * N3 + idx) = acc[o];
    STATS_REDUCE(stats);
}

__global__ __launch_bounds__(256) void bn_gate_kernel(const float* __restrict__ zp,
                                                      const float* __restrict__ stats,
                                                      const float* __restrict__ wsc,
                                                      const float* __restrict__ bsc,
                                                      const float* __restrict__ wvc,
                                                      float* __restrict__ out) {
    __shared__ float sb[56];
    FINALIZE_SB(stats, wsc, bsc, wvc);

    int idx = (blockIdx.x * 256 + threadIdx.x) * 2;
    float2 g[8];
    #pragma unroll
    for (int u = 0; u < 8; u++) {
        float2 v = *(const float2*)(zp + (16 + u) * N3 + idx);
        float sc = sb[16 + u], bi = sb[40 + u];
        g[u].x = sigm(v.x * sc + bi);
        g[u].y = sigm(v.y * sc + bi);
    }
    #pragma unroll
    for (int c = 0; c < 16; c++) {
        float2 v = *(const float2*)(zp + c * N3 + idx);
        float sc = sb[c], bi = sb[24 + c];
        float2 r;
        r.x = fmaxf(v.x * sc + bi, 0.f);
        r.y = fmaxf(v.y * sc + bi, 0.f);
        *(float2*)(out + c * N3 + idx) = r;
    }
    #pragma unroll
    for (int u = 0; u < 8; u++) {
        float sv = sb[48 + u];
        #pragma unroll
        for (int m = 0; m < 3; m++) {
            float2 v = *(const float2*)(zp + (24 + u * 3 + m) * N3 + idx);
            float2 r;
            r.x = v.x * sv * g[u].x;
            r.y = v.y * sv * g[u].y;
            *(float2*)(out + (16 + u * 3 + m) * N3 + idx) = r;
        }
    }
}

// ---------------------------------------------------------------------------
// FUSED kernels (cooperative, 1-D grid of 512 blocks; bid<256 -> ohalf 0)
// ---------------------------------------------------------------------------
__global__ __launch_bounds__(256, 2) void conv1_fused(
        const float* __restrict__ x, const float* __restrict__ Tg,
        float* __restrict__ y, float* __restrict__ gbuf,
        float* __restrict__ stats,
        const float* __restrict__ wsc, const float* __restrict__ bsc,
        const float* __restrict__ wvc) {
    __shared__ float T[448];
    __shared__ float red[4][48];
    __shared__ float sb[56];
    for (int t = threadIdx.x; t < 448; t += 256) T[t] = Tg[t];
    __syncthreads();

    const int bid = blockIdx.x;
    const int ohalf = bid >> 8;
    int idx = (bid & 255) * 1024 + threadIdx.x * 4;
    int w0 = idx & 63, h = (idx >> 6) & 63, d = idx >> 12;
    bool dmok = d > 0, dpok = d < 63, hmok = h > 0, hpok = h < 63;
    bool wL = (w0 == 0), wR = (w0 == 60);

    float4 acc[24];
    #pragma unroll
    for (int o = 0; o < 24; o++) acc[o] = f4z();
    CONV1_BODY(x);

    if (ohalf == 0) {
        #pragma unroll
        for (int u = 0; u < 8; u++)
            *(float4*)(gbuf + u * N3 + idx) = acc[16 + u];
    }
    STATS_REDUCE(stats);

    __threadfence();
    cg::this_grid().sync();

    FINALIZE_SB(stats, wsc, bsc, wvc);
    GATED_EPILOGUE(y, gbuf);
}

__global__ __launch_bounds__(256, 2) void conv2_fused(
        const float* __restrict__ y, const float* __restrict__ Tg,
        float* __restrict__ out, float* __restrict__ gbuf,
        float* __restrict__ stats,
        const float* __restrict__ wsc, const float* __restrict__ bsc,
        const float* __restrict__ wvc) {
    __shared__ float T[1280];
    __shared__ float red[4][48];
    __shared__ float sb[56];
    for (int t = threadIdx.x; t < 1280; t += 256) T[t] = Tg[448 + t];
    __syncthreads();

    const int bid = blockIdx.x;
    const int ohalf = bid >> 8;
    int idx = (bid & 255) * 1024 + threadIdx.x * 4;
    int w0 = idx & 63, h = (idx >> 6) & 63, d = idx >> 12;
    bool dmok = d > 0, dpok = d < 63, hmok = h > 0, hpok = h < 63;
    bool wL = (w0 == 0), wR = (w0 == 60);

    float4 acc[24];
    #pragma unroll
    for (int o = 0; o < 24; o++) acc[o] = f4z();
    CONV2_BODY(y);

    if (ohalf == 0) {
        #pragma unroll
        for (int u = 0; u < 8; u++)
            *(float4*)(gbuf + u * N3 + idx) = acc[16 + u];
    }
    STATS_REDUCE(stats);

    __threadfence();
    cg::this_grid().sync();   // all conv reads of y complete -> in-place write safe

    FINALIZE_SB(stats, wsc, bsc, wvc);
    GATED_EPILOGUE(out, gbuf);
}

// ---------------------------------------------------------------------------
extern "C" void kernel_launch(void* const* d_in, const int* in_sizes, int n_in,
                              void* d_out, int out_size, void* d_ws, size_t ws_size,
                              hipStream_t stream) {
    const float* x      = (const float*)d_in[0];
    const float* w1     = (const float*)d_in[1];
    const float* sc1    = (const float*)d_in[2];
    const float* w2     = (const float*)d_in[3];
    const float* sc2s   = (const float*)d_in[4];
    const float* sc2v   = (const float*)d_in[5];
    const float* bn1_ws = (const float*)d_in[6];
    const float* bn1_bs = (const float*)d_in[7];
    const float* bn1_wv = (const float*)d_in[8];
    const float* bn2_ws = (const float*)d_in[9];
    const float* bn2_bs = (const float*)d_in[10];
    const float* bn2_wv = (const float*)d_in[11];
    float* out = (float*)d_out;
    char* ws = (char*)d_ws;

    float* Tg     = (float*)(ws + 0);        // 1728 floats
    float* stats1 = (float*)(ws + 8192);
    float* stats2 = (float*)(ws + 8192 + 512);
    float* zbuf   = (float*)(ws + 262144);   // 48ch zpre (fallback) / gbuf (fused)
    float* gbuf   = zbuf;                    // 8ch, aliases zbuf (exclusive use)

    hipLaunchKernelGGL(build_tables_kernel, dim3(8), dim3(256), 0, stream,
                       w1, sc1, w2, sc2s, sc2v, Tg, stats1, stats2);

    // ---- pass 1: x -> y (y lives in d_out) ----
    {
        void* args[] = {(void*)&x, (void*)&Tg, (void*)&out, (void*)&gbuf,
                        (void*)&stats1, (void*)&bn1_ws, (void*)&bn1_bs, (void*)&bn1_wv};
        hipError_t e = hipLaunchCooperativeKernel((const void*)conv1_fused,
                                                  dim3(512), dim3(256), args, 0, stream);
        if (e != hipSuccess) {
            (void)hipGetLastError();  // clear sticky error
            hipLaunchKernelGGL(conv1_plain, dim3(256, 2), dim3(256), 0, stream,
                               x, Tg, zbuf, stats1);
            hipLaunchKernelGGL(bn_gate_kernel, dim3(512), dim3(256), 0, stream,
                               zbuf, stats1, bn1_ws, bn1_bs, bn1_wv, out);
        }
    }

    // ---- pass 2: y (d_out) -> out (d_out, in-place via grid barrier) ----
    {
        const float* yin = (const float*)out;
        void* args[] = {(void*)&yin, (void*)&Tg, (void*)&out, (void*)&gbuf,
                        (void*)&stats2, (void*)&bn2_ws, (void*)&bn2_bs, (void*)&bn2_wv};
        hipError_t e = hipLaunchCooperativeKernel((const void*)conv2_fused,
                                                  dim3(512), dim3(256), args, 0, stream);
        if (e != hipSuccess) {
            (void)hipGetLastError();
            hipLaunchKernelGGL(conv2_plain, dim3(256, 2), dim3(256), 0, stream,
                               out, Tg, zbuf, stats2);
            hipLaunchKernelGGL(bn_gate_kernel, dim3(512), dim3(256), 0, stream,
                               zbuf, stats2, bn2_ws, bn2_bs, bn2_wv, out);
        }
    }
}

// Round 18
// 109.187 us; speedup vs baseline: 3.9075x; 3.9075x over previous
//
#include <hip/hip_runtime.h>
#include <math.h>

#define N3 262144           // 64^3

// ===========================================================================
// Derived-feature formulation (verified R4-R15): 7-point stencil; per input
// row the conv depends only on c (center), S (sum of 6 faces), D_A (diffs).
// R16/R17: cooperative fusion spills acc across grid.sync (800MB scratch) —
// fusion closed. R18 (this): R15 verified structure + XCD-aware block swizzle
// (8 contiguous d-planes per XCD -> d+-1 taps become L2 hits, not L3).
// ===========================================================================

// Table layout (floats):
// conv1 (448): T1c[8][24]@0, T1f[8][24]@192, T1v[8][8]@384
// conv2 (1280)@448: T2c[16][24]@+0, T2f[16][24]@+384, T2sv[16][8]@+768,
//   T2vs[8][24]@+896, T2v0c[8][8]@+1088, T2v0f[8][8]@+1152, T2v1[8][8]@+1216
#define TBL_TOTAL 1728

__device__ inline void lattice_emb(int p, float* embr) {
    int i = p / 9, j = (p / 3) % 3, k = p % 3;
    float gx = (float)(i - 1), gy = (float)(j - 1), gz = (float)(k - 1);
    float r = sqrtf(gx * gx + gy * gy + gz * gz);
    const float centers[4] = {0.f, 0.33333334f, 0.6666667f, 1.f};
    const float step = 0.33333334f;
    #pragma unroll
    for (int b = 0; b < 4; b++) {
        float dd = (r - centers[b]) / step;
        float e = 0.f;
        if (fabsf(dd) < 1.f)
            e = 1.14136f * expf(2.f) * expf(-1.f / fmaxf(1.f - dd * dd, 1e-9f));
        embr[b] = e;
    }
}

// Also zeroes the BN stats buffers (threads TBL_TOTAL..TBL_TOTAL+143).
__global__ __launch_bounds__(256) void build_tables_kernel(
        const float* __restrict__ w1,  const float* __restrict__ sc1,
        const float* __restrict__ w2,  const float* __restrict__ sc2s,
        const float* __restrict__ sc2v, float* __restrict__ T,
        float* __restrict__ stats1, float* __restrict__ stats2) {
    int gid = blockIdx.x * 256 + threadIdx.x;
    if (gid >= TBL_TOTAL) {
        int r = gid - TBL_TOTAL;
        if (r < 72) stats1[r] = 0.f;
        else if (r < 144) stats2[r - 72] = 0.f;
        return;
    }

    const float inv_ks15 = 0.19245008972987526f;  // 1/3^1.5
    const float s3   = 1.7320508075688772f;
    const float a1   = 0.35355339059327373f;  // 1/sqrt(8)
    const float a_s  = 0.2041241452319315f;   // 1/sqrt(24)
    const float a_v  = 0.17677669529663687f;  // 1/sqrt(32)
    const float a_s3 = 0.11785113019775793f;  // a_s/sqrt(3)
    const float a_v6 = 0.07216878364870322f;  // a_v/sqrt(6)

    float embC[4], embF[4];
    lattice_emb(13, embC);   // center (r=0)
    lattice_emb(22, embF);   // face   (r=1), shared by all 6 faces

    auto WC1 = [&](int c) { float s=0.f;
        #pragma unroll
        for (int b=0;b<4;b++) s += embC[b]*w1[b*256+c]; return s*inv_ks15; };
    auto WF1 = [&](int c) { float s=0.f;
        #pragma unroll
        for (int b=0;b<4;b++) s += embF[b]*w1[b*256+c]; return s*inv_ks15; };
    auto WC2 = [&](int c) { float s=0.f;
        #pragma unroll
        for (int b=0;b<4;b++) s += embC[b]*w2[b*832+c]; return s*inv_ks15; };
    auto WF2 = [&](int c) { float s=0.f;
        #pragma unroll
        for (int b=0;b<4;b++) s += embF[b]*w2[b*832+c]; return s*inv_ks15; };

    float val = 0.f;
    if (gid < 192) {                       // T1c
        int i = gid / 24, o = gid % 24;
        int c = (o < 16) ? i * 16 + o : 128 + i * 8 + (o - 16);
        val = a1 * WC1(c) + a1 * sc1[i * 24 + o];
    } else if (gid < 384) {                // T1f
        int r = gid - 192; int i = r / 24, o = r % 24;
        int c = (o < 16) ? i * 16 + o : 128 + i * 8 + (o - 16);
        val = a1 * WF1(c);
    } else if (gid < 448) {                // T1v
        int r = gid - 384; int i = r / 8, jj = r % 8;
        val = a1 * s3 * WF1(192 + i * 8 + jj);
    } else if (gid < 832) {                // T2c
        int r = gid - 448; int i = r / 24, o = r % 24;
        int c = (o < 16) ? i * 16 + o : 256 + i * 8 + (o - 16);
        val = a_s * WC2(c) + 0.25f * sc2s[i * 24 + o];
    } else if (gid < 1216) {               // T2f
        int r = gid - 832; int i = r / 24, o = r % 24;
        int c = (o < 16) ? i * 16 + o : 256 + i * 8 + (o - 16);
        val = a_s * WF2(c);
    } else if (gid < 1344) {               // T2sv
        int r = gid - 1216; int i = r / 8, jj = r % 8;
        val = a_v * s3 * WF2(384 + i * 8 + jj);
    } else if (gid < 1536) {               // T2vs
        int r = gid - 1344; int u = r / 24, o = r % 24;
        int c = (o < 16) ? 576 + u * 16 + o : 704 + u * 8 + (o - 16);
        val = a_s3 * s3 * WF2(c);
    } else if (gid < 1600) {               // T2v0c
        int r = gid - 1536; int u = r / 8, jj = r % 8;
        val = a_v * WC2(512 + u * 8 + jj) + a1 * sc2v[u * 8 + jj];
    } else if (gid < 1664) {               // T2v0f
        int r = gid - 1600; int u = r / 8, jj = r % 8;
        val = a_v * WF2(512 + u * 8 + jj);
    } else {                               // T2v1
        int r = gid - 1664; int u = r / 8, jj = r % 8;
        val = a_v6 * s3 * WF2(768 + u * 8 + jj);
    }
    T[gid] = val;
}

// ---------------------------------------------------------------------------
// float4 helpers
// ---------------------------------------------------------------------------
__device__ inline float4 f4z() { return make_float4(0.f, 0.f, 0.f, 0.f); }
__device__ inline float4 f4add(float4 a, float4 b) {
    return make_float4(a.x+b.x, a.y+b.y, a.z+b.z, a.w+b.w); }
__device__ inline float4 f4sub(float4 a, float4 b) {
    return make_float4(a.x-b.x, a.y-b.y, a.z-b.z, a.w-b.w); }
__device__ inline float4 f4fma(float s, float4 a, float4 c) {
    return make_float4(fmaf(s,a.x,c.x), fmaf(s,a.y,c.y), fmaf(s,a.z,c.z), fmaf(s,a.w,c.w)); }
__device__ inline float f4sum(float4 a) { return a.x+a.y+a.z+a.w; }
__device__ inline float f4dot(float4 a) { return a.x*a.x+a.y*a.y+a.z*a.z+a.w*a.w; }

// Load quads for c, d+-, h+- of one channel row
#define LQ5(BP, C_, DM_, DP_, HM_, HP_)                                       \
    {                                                                         \
        const float* _p = (BP);                                               \
        C_  = *(const float4*)_p;                                             \
        DM_ = dmok ? *(const float4*)(_p - 4096) : f4z();                     \
        DP_ = dpok ? *(const float4*)(_p + 4096) : f4z();                     \
        HM_ = hmok ? *(const float4*)(_p -   64) : f4z();                     \
        HP_ = hpok ? *(const float4*)(_p +   64) : f4z();                     \
    }

// w-neighbor quads from c (in-quad shifts + cross-lane shfl at quad edges)
#define WQ(C_, WM_, WP_)                                                      \
    {                                                                         \
        float _lw = __shfl_up((C_).w, 1, 64);                                 \
        float _rw = __shfl_down((C_).x, 1, 64);                               \
        WM_ = make_float4(wL ? 0.f : _lw, (C_).x, (C_).y, (C_).z);            \
        WP_ = make_float4((C_).y, (C_).z, (C_).w, wR ? 0.f : _rw);            \
    }

// XCD-aware swizzle for 256-block grids: 8 XCDs x 32 contiguous blocks.
// Contiguous d-planes stay on one XCD -> d+-1 taps hit that XCD's L2.
__device__ inline int xcd_swz(int bx) { return (bx & 7) * 32 + (bx >> 3); }

// ---------------------------------------------------------------------------
// conv1: x(8,64^3) -> ypre(48,64^3). 4 pts/thread, channel-half split,
// 256-thread blocks (16 w-rows), XCD swizzle.
// ---------------------------------------------------------------------------
__global__ __launch_bounds__(256, 2) void conv1_kernel(const float* __restrict__ x,
                                                       const float* __restrict__ Tg,
                                                       float* __restrict__ out,
                                                       float* __restrict__ stats) {
    __shared__ float T[448];
    __shared__ float red[4][48];
    for (int t = threadIdx.x; t < 448; t += 256) T[t] = Tg[t];
    __syncthreads();

    const int ohalf = blockIdx.y;
    int idx = xcd_swz(blockIdx.x) * 1024 + threadIdx.x * 4;
    int w0 = idx & 63, h = (idx >> 6) & 63, d = idx >> 12;
    bool dmok = d > 0, dpok = d < 63, hmok = h > 0, hpok = h < 63;
    bool wL = (w0 == 0), wR = (w0 == 60);

    float4 acc[24];
    #pragma unroll
    for (int o = 0; o < 24; o++) acc[o] = f4z();

    float4 nc, ndm, ndp, nhm, nhp;
    LQ5(x + idx, nc, ndm, ndp, nhm, nhp);

    if (ohalf == 0) {
        #pragma unroll 1
        for (int i = 0; i < 8; i++) {
            float4 c = nc, dmq = ndm, dpq = ndp, hmq = nhm, hpq = nhp;
            if (i < 7) LQ5(x + (i + 1) * N3 + idx, nc, ndm, ndp, nhm, nhp);
            float4 wmq, wpq; WQ(c, wmq, wpq);
            float4 S = f4add(f4add(f4add(dmq, dpq), f4add(hmq, hpq)), f4add(wmq, wpq));
            const float* tc = &T[i * 24];
            const float* tf = &T[192 + i * 24];
            #pragma unroll
            for (int o = 0; o < 24; o++)
                acc[o] = f4fma(tc[o], c, f4fma(tf[o], S, acc[o]));
        }
    } else {
        #pragma unroll 1
        for (int i = 0; i < 8; i++) {
            float4 c = nc, dmq = ndm, dpq = ndp, hmq = nhm, hpq = nhp;
            if (i < 7) LQ5(x + (i + 1) * N3 + idx, nc, ndm, ndp, nhm, nhp);
            float4 wmq, wpq; WQ(c, wmq, wpq);
            float4 Dd = f4sub(dpq, dmq), Dh = f4sub(hpq, hmq), Dw = f4sub(wpq, wmq);
            const float* tv = &T[384 + i * 8];
            #pragma unroll
            for (int jj = 0; jj < 8; jj++) {
                float wv = tv[jj];
                acc[jj * 3 + 0] = f4fma(wv, Dd, acc[jj * 3 + 0]);
                acc[jj * 3 + 1] = f4fma(wv, Dh, acc[jj * 3 + 1]);
                acc[jj * 3 + 2] = f4fma(wv, Dw, acc[jj * 3 + 2]);
            }
        }
    }

    int obase = ohalf * 24;
    #pragma unroll
    for (int o = 0; o < 24; o++)
        *(float4*)(out + (obase + o) * N3 + idx) = acc[o];

    // fused BN partial stats
    int lane = threadIdx.x & 63, wvx = threadIdx.x >> 6;
    if (ohalf == 0) {
        #pragma unroll
        for (int q = 0; q < 48; q++) {
            float val = (q < 24) ? f4sum(acc[q]) : f4dot(acc[q - 24]);
            #pragma unroll
            for (int mq = 32; mq >= 1; mq >>= 1) val += __shfl_xor(val, mq, 64);
            if (lane == 0) red[wvx][q] = val;
        }
        __syncthreads();
        if (threadIdx.x < 48)
            atomicAdd(&stats[threadIdx.x],
                      red[0][threadIdx.x] + red[1][threadIdx.x] +
                      red[2][threadIdx.x] + red[3][threadIdx.x]);
    } else {
        #pragma unroll
        for (int q = 0; q < 24; q++) {
            float val = f4dot(acc[q]);
            #pragma unroll
            for (int mq = 32; mq >= 1; mq >>= 1) val += __shfl_xor(val, mq, 64);
            if (lane == 0) red[wvx][q] = val;
        }
        __syncthreads();
        if (threadIdx.x < 24)
            atomicAdd(&stats[48 + threadIdx.x],
                      red[0][threadIdx.x] + red[1][threadIdx.x] +
                      red[2][threadIdx.x] + red[3][threadIdx.x]);
    }
}

// ---------------------------------------------------------------------------
// conv2: y(40,64^3) -> zpre(48,64^3). 4 pts/thread, channel-half split,
// 256-thread blocks (16 w-rows), XCD swizzle.
// ---------------------------------------------------------------------------
__global__ __launch_bounds__(256, 2) void conv2_kernel(const float* __restrict__ y,
                                                       const float* __restrict__ Tg,
                                                       float* __restrict__ out,
                                                       float* __restrict__ stats) {
    __shared__ float T[1280];
    __shared__ float red[4][48];
    for (int t = threadIdx.x; t < 1280; t += 256) T[t] = Tg[448 + t];
    __syncthreads();

    const int ohalf = blockIdx.y;
    int idx = xcd_swz(blockIdx.x) * 1024 + threadIdx.x * 4;
    int w0 = idx & 63, h = (idx >> 6) & 63, d = idx >> 12;
    bool dmok = d > 0, dpok = d < 63, hmok = h > 0, hpok = h < 63;
    bool wL = (w0 == 0), wR = (w0 == 60);

    float4 acc[24];
    #pragma unroll
    for (int o = 0; o < 24; o++) acc[o] = f4z();

    if (ohalf == 0) {
        // ---- scalar rows: c,S -> tc/tf ----
        float4 nc, ndm, ndp, nhm, nhp;
        LQ5(y + idx, nc, ndm, ndp, nhm, nhp);
        #pragma unroll 1
        for (int i = 0; i < 16; i++) {
            float4 c = nc, dmq = ndm, dpq = ndp, hmq = nhm, hpq = nhp;
            if (i < 15) LQ5(y + (i + 1) * N3 + idx, nc, ndm, ndp, nhm, nhp);
            float4 wmq, wpq; WQ(c, wmq, wpq);
            float4 S = f4add(f4add(f4add(dmq, dpq), f4add(hmq, hpq)), f4add(wmq, wpq));
            const float* tc = &T[i * 24];
            const float* tf = &T[384 + i * 24];
            #pragma unroll
            for (int o = 0; o < 24; o++)
                acc[o] = f4fma(tc[o], c, f4fma(tf[o], S, acc[o]));
        }
        // ---- vector rows: only Dsum needed (divergence) ----
        #pragma unroll 1
        for (int u = 0; u < 8; u++) {
            const float* b0 = y + (16 + u * 3) * N3 + idx;
            float4 qdm = dmok ? *(const float4*)(b0 - 4096) : f4z();
            float4 qdp = dpok ? *(const float4*)(b0 + 4096) : f4z();
            float4 qhm = hmok ? *(const float4*)(b0 + N3 - 64) : f4z();
            float4 qhp = hpok ? *(const float4*)(b0 + N3 + 64) : f4z();
            float4 c2  = *(const float4*)(b0 + 2 * N3);
            float4 wmq, wpq; WQ(c2, wmq, wpq);
            float4 Dsum = f4add(f4add(f4sub(qdp, qdm), f4sub(qhp, qhm)), f4sub(wpq, wmq));
            const float* tvs = &T[896 + u * 24];
            #pragma unroll
            for (int o = 0; o < 24; o++)
                acc[o] = f4fma(tvs[o], Dsum, acc[o]);
        }
    } else {
        // ---- scalar rows: D only -> T2sv ----
        float4 nc, ndm, ndp, nhm, nhp;
        LQ5(y + idx, nc, ndm, ndp, nhm, nhp);
        #pragma unroll 1
        for (int i = 0; i < 16; i++) {
            float4 c = nc, dmq = ndm, dpq = ndp, hmq = nhm, hpq = nhp;
            if (i < 15) LQ5(y + (i + 1) * N3 + idx, nc, ndm, ndp, nhm, nhp);
            float4 wmq, wpq; WQ(c, wmq, wpq);
            float4 Dd = f4sub(dpq, dmq), Dh = f4sub(hpq, hmq), Dw = f4sub(wpq, wmq);
            const float* tv = &T[768 + i * 8];
            #pragma unroll
            for (int jj = 0; jj < 8; jj++) {
                float wv = tv[jj];
                acc[jj * 3 + 0] = f4fma(wv, Dd, acc[jj * 3 + 0]);
                acc[jj * 3 + 1] = f4fma(wv, Dh, acc[jj * 3 + 1]);
                acc[jj * 3 + 2] = f4fma(wv, Dw, acc[jj * 3 + 2]);
            }
        }
        // ---- vector rows: vv0 + vv1, 3 explicit m-blocks per u ----
        #pragma unroll 1
        for (int u = 0; u < 8; u++) {
            const float* t0c = &T[1088 + u * 8];
            const float* t0f = &T[1152 + u * 8];
            const float* tv1 = &T[1216 + u * 8];
            {   // m=0: vv0 -> comp0; +k1*Dh -> comp2; -k1*Dw -> comp1
                float4 c, dmq, dpq, hmq, hpq;
                LQ5(y + (16 + u * 3 + 0) * N3 + idx, c, dmq, dpq, hmq, hpq);
                float4 wmq, wpq; WQ(c, wmq, wpq);
                float4 S = f4add(f4add(f4add(dmq, dpq), f4add(hmq, hpq)), f4add(wmq, wpq));
                float4 Dh = f4sub(hpq, hmq), Dw = f4sub(wpq, wmq);
                #pragma unroll
                for (int jj = 0; jj < 8; jj++) {
                    float k1 = tv1[jj];
                    acc[jj * 3 + 0] = f4fma(t0c[jj], c, f4fma(t0f[jj], S, acc[jj * 3 + 0]));
                    acc[jj * 3 + 2] = f4fma(k1, Dh, acc[jj * 3 + 2]);
                    acc[jj * 3 + 1] = f4fma(-k1, Dw, acc[jj * 3 + 1]);
                }
            }
            {   // m=1: vv0 -> comp1; +k1*Dw -> comp0; -k1*Dd -> comp2
                float4 c, dmq, dpq, hmq, hpq;
                LQ5(y + (16 + u * 3 + 1) * N3 + idx, c, dmq, dpq, hmq, hpq);
                float4 wmq, wpq; WQ(c, wmq, wpq);
                float4 S = f4add(f4add(f4add(dmq, dpq), f4add(hmq, hpq)), f4add(wmq, wpq));
                float4 Dd = f4sub(dpq, dmq), Dw = f4sub(wpq, wmq);
                #pragma unroll
                for (int jj = 0; jj < 8; jj++) {
                    float k1 = tv1[jj];
                    acc[jj * 3 + 1] = f4fma(t0c[jj], c, f4fma(t0f[jj], S, acc[jj * 3 + 1]));
                    acc[jj * 3 + 0] = f4fma(k1, Dw, acc[jj * 3 + 0]);
                    acc[jj * 3 + 2] = f4fma(-k1, Dd, acc[jj * 3 + 2]);
                }
            }
            {   // m=2: vv0 -> comp2; +k1*Dd -> comp1; -k1*Dh -> comp0
                float4 c, dmq, dpq, hmq, hpq;
                LQ5(y + (16 + u * 3 + 2) * N3 + idx, c, dmq, dpq, hmq, hpq);
                float4 wmq, wpq; WQ(c, wmq, wpq);
                float4 S = f4add(f4add(f4add(dmq, dpq), f4add(hmq, hpq)), f4add(wmq, wpq));
                float4 Dd = f4sub(dpq, dmq), Dh = f4sub(hpq, hmq);
                #pragma unroll
                for (int jj = 0; jj < 8; jj++) {
                    float k1 = tv1[jj];
                    acc[jj * 3 + 2] = f4fma(t0c[jj], c, f4fma(t0f[jj], S, acc[jj * 3 + 2]));
                    acc[jj * 3 + 1] = f4fma(k1, Dd, acc[jj * 3 + 1]);
                    acc[jj * 3 + 0] = f4fma(-k1, Dh, acc[jj * 3 + 0]);
                }
            }
        }
    }

    int obase = ohalf * 24;
    #pragma unroll
    for (int o = 0; o < 24; o++)
        *(float4*)(out + (obase + o) * N3 + idx) = acc[o];

    // fused BN partial stats
    int lane = threadIdx.x & 63, wvx = threadIdx.x >> 6;
    if (ohalf == 0) {
        #pragma unroll
        for (int q = 0; q < 48; q++) {
            float val = (q < 24) ? f4sum(acc[q]) : f4dot(acc[q - 24]);
            #pragma unroll
            for (int mq = 32; mq >= 1; mq >>= 1) val += __shfl_xor(val, mq, 64);
            if (lane == 0) red[wvx][q] = val;
        }
        __syncthreads();
        if (threadIdx.x < 48)
            atomicAdd(&stats[threadIdx.x],
                      red[0][threadIdx.x] + red[1][threadIdx.x] +
                      red[2][threadIdx.x] + red[3][threadIdx.x]);
    } else {
        #pragma unroll
        for (int q = 0; q < 24; q++) {
            float val = f4dot(acc[q]);
            #pragma unroll
            for (int mq = 32; mq >= 1; mq >>= 1) val += __shfl_xor(val, mq, 64);
            if (lane == 0) red[wvx][q] = val;
        }
        __syncthreads();
        if (threadIdx.x < 24)
            atomicAdd(&stats[48 + threadIdx.x],
                      red[0][threadIdx.x] + red[1][threadIdx.x] +
                      red[2][threadIdx.x] + red[3][threadIdx.x]);
    }
}

// ---------------------------------------------------------------------------
// BN apply + gate (finalize inlined): zp(48ch) -> out(40ch), float2/thread
// ---------------------------------------------------------------------------
__global__ __launch_bounds__(256) void bn_gate_kernel(const float* __restrict__ zp,
                                                      const float* __restrict__ stats,
                                                      const float* __restrict__ wsc,
                                                      const float* __restrict__ bsc,
                                                      const float* __restrict__ wvc,
                                                      float* __restrict__ out) {
    __shared__ float sb[56];
    if (threadIdx.x < 32) {
        int t = threadIdx.x;
        const float invN = 1.0f / 262144.0f;
        if (t < 24) {
            float mu = stats[t] * invN;
            float var = stats[24 + t] * invN - mu * mu;
            float inv = rsqrtf(var + 1e-5f);
            sb[t] = wsc[t] * inv;
            sb[24 + t] = bsc[t] - mu * wsc[t] * inv;
        } else {
            int u = t - 24;
            float s2 = stats[48 + u * 3] + stats[48 + u * 3 + 1] + stats[48 + u * 3 + 2];
            sb[48 + u] = wvc[u] * rsqrtf(s2 * invN + 1e-5f);
        }
    }
    __syncthreads();

    int idx = (blockIdx.x * 256 + threadIdx.x) * 2;
    float2 g[8];
    #pragma unroll
    for (int u = 0; u < 8; u++) {
        float2 v = *(const float2*)(zp + (16 + u) * N3 + idx);
        float sc = sb[16 + u], bi = sb[40 + u];
        g[u].x = 1.0f / (1.0f + expf(-(v.x * sc + bi)));
        g[u].y = 1.0f / (1.0f + expf(-(v.y * sc + bi)));
    }
    #pragma unroll
    for (int c = 0; c < 16; c++) {
        float2 v = *(const float2*)(zp + c * N3 + idx);
        float sc = sb[c], bi = sb[24 + c];
        float2 r;
        r.x = fmaxf(v.x * sc + bi, 0.f);
        r.y = fmaxf(v.y * sc + bi, 0.f);
        *(float2*)(out + c * N3 + idx) = r;
    }
    #pragma unroll
    for (int u = 0; u < 8; u++) {
        float sv = sb[48 + u];
        #pragma unroll
        for (int m = 0; m < 3; m++) {
            float2 v = *(const float2*)(zp + (24 + u * 3 + m) * N3 + idx);
            float2 r;
            r.x = v.x * sv * g[u].x;
            r.y = v.y * sv * g[u].y;
            *(float2*)(out + (16 + u * 3 + m) * N3 + idx) = r;
        }
    }
}

// ---------------------------------------------------------------------------
extern "C" void kernel_launch(void* const* d_in, const int* in_sizes, int n_in,
                              void* d_out, int out_size, void* d_ws, size_t ws_size,
                              hipStream_t stream) {
    const float* x      = (const float*)d_in[0];
    const float* w1     = (const float*)d_in[1];
    const float* sc1    = (const float*)d_in[2];
    const float* w2     = (const float*)d_in[3];
    const float* sc2s   = (const float*)d_in[4];
    const float* sc2v   = (const float*)d_in[5];
    const float* bn1_ws = (const float*)d_in[6];
    const float* bn1_bs = (const float*)d_in[7];
    const float* bn1_wv = (const float*)d_in[8];
    const float* bn2_ws = (const float*)d_in[9];
    const float* bn2_bs = (const float*)d_in[10];
    const float* bn2_wv = (const float*)d_in[11];
    float* out = (float*)d_out;
    char* ws = (char*)d_ws;

    float* Tg     = (float*)(ws + 0);        // 1728 floats
    float* stats1 = (float*)(ws + 8192);     // 72 floats
    float* stats2 = (float*)(ws + 8192 + 512);
    float* bufA   = (float*)(ws + 262144);   // 48*N3*4 = 50331648 B

    hipLaunchKernelGGL(build_tables_kernel, dim3(8), dim3(256), 0, stream,
                       w1, sc1, w2, sc2s, sc2v, Tg, stats1, stats2);
    hipLaunchKernelGGL(conv1_kernel, dim3(256, 2), dim3(256), 0, stream, x, Tg, bufA, stats1);
    hipLaunchKernelGGL(bn_gate_kernel, dim3(512), dim3(256), 0, stream,
                       bufA, stats1, bn1_ws, bn1_bs, bn1_wv, out);
    hipLaunchKernelGGL(conv2_kernel, dim3(256, 2), dim3(256), 0, stream, out, Tg, bufA, stats2);
    hipLaunchKernelGGL(bn_gate_kernel, dim3(512), dim3(256), 0, stream,
                       bufA, stats2, bn2_ws, bn2_bs, bn2_wv, out);
}